// Round 10
// baseline (353.388 us; speedup 1.0000x reference)
//
#include <hip/hip_runtime.h>

#define N_NODES 50000
#define N_EDGES 600000
#define NBLK    196           // (N_NODES+255)/256
#define KDIM    128
#define APAD    136           // 128 + 8 ushorts pad (272B row stride -> 2-way banks, free)

typedef short bf16x8 __attribute__((ext_vector_type(8)));
typedef float f32x4  __attribute__((ext_vector_type(4)));
typedef unsigned short u16x8 __attribute__((ext_vector_type(8)));
typedef unsigned short u16x4 __attribute__((ext_vector_type(4)));

// ---------------- bf16 helpers (RNE) ----------------
__device__ inline ushort rne_bf16(float a) {
    union { float f; unsigned u; } v; v.f = a;
    return (ushort)((v.u + 0x7FFFu + ((v.u >> 16) & 1u)) >> 16);
}
__device__ inline float bf16_to_f32(ushort h) {
    return __uint_as_float((unsigned)h << 16);
}
__device__ inline void split_bf16(float a, ushort& hi, ushort& lo) {
    hi = rne_bf16(a);
    float hv = bf16_to_f32(hi);
    lo = rne_bf16(a - hv);
}

// =============== K1: fused count_deg || convert_w ===============
__global__ __launch_bounds__(256) void k_prep(
    const int* __restrict__ dst, int* __restrict__ degi,
    const float* __restrict__ ws0, const float* __restrict__ wn0,
    const float* __restrict__ ws1, const float* __restrict__ wn1,
    const float* __restrict__ ws2, const float* __restrict__ wn2,
    ushort* __restrict__ Bth0, ushort* __restrict__ Btl0,
    ushort* __restrict__ Bth1, ushort* __restrict__ Btl1,
    ushort* __restrict__ Bth2, ushort* __restrict__ Btl2)
{
    const int b = blockIdx.x, t = threadIdx.x;
    if (b < 192) {
        for (int e = b * 256 + t; e < N_EDGES; e += 192 * 256)
            atomicAdd(&degi[dst[e]], 1);
    } else {
        for (int i = (b - 192) * 256 + t; i < 592 * 128; i += 64 * 256) {
            int bb = i >> 7, k = i & 127;
            const float *Ws, *Wn;
            ushort *H, *L;
            int dout, n;
            if (bb < 256)      { n = bb;       dout = 128; Ws = ws0; Wn = wn0; H = Bth0; L = Btl0; }
            else if (bb < 512) { n = bb - 256; dout = 128; Ws = ws1; Wn = wn1; H = Bth1; L = Btl1; }
            else               { n = bb - 512; dout = 40;  Ws = ws2; Wn = wn2; H = Bth2; L = Btl2; }
            float w = (n < dout) ? Ws[(long)k * dout + n] : Wn[(long)k * dout + (n - dout)];
            ushort hi, lo;
            split_bf16(w, hi, lo);
            H[n * 128 + k] = hi;
            L[n * 128 + k] = lo;
        }
    }
}

// =============== CSR scan kernels ===============
__global__ __launch_bounds__(256) void block_sums_kernel(const int* __restrict__ deg,
                                                         int* __restrict__ bsum, int n) {
    __shared__ int s[256];
    int t = threadIdx.x;
    int i = blockIdx.x * 256 + t;
    s[t] = (i < n) ? deg[i] : 0;
    __syncthreads();
    #pragma unroll
    for (int d = 128; d > 0; d >>= 1) {
        if (t < d) s[t] += s[t + d];
        __syncthreads();
    }
    if (t == 0) bsum[blockIdx.x] = s[0];
}

__global__ __launch_bounds__(256) void scatter_fused_kernel(const int* __restrict__ deg,
                                                            const int* __restrict__ bsum,
                                                            int* __restrict__ off,
                                                            int* __restrict__ cur,
                                                            int n, int nb) {
    __shared__ int s[256];
    int t = threadIdx.x;

    int bv = (t < nb) ? bsum[t] : 0;
    s[t] = bv;
    __syncthreads();
    #pragma unroll
    for (int d = 1; d < 256; d <<= 1) {
        int x = (t >= d) ? s[t - d] : 0;
        __syncthreads();
        s[t] += x;
        __syncthreads();
    }
    int base = (blockIdx.x > 0) ? s[blockIdx.x - 1] : 0;
    if (blockIdx.x == 0 && t == 0) off[n] = s[255];
    __syncthreads();

    int i = blockIdx.x * 256 + t;
    int v = (i < n) ? deg[i] : 0;
    s[t] = v;
    __syncthreads();
    #pragma unroll
    for (int d = 1; d < 256; d <<= 1) {
        int x = (t >= d) ? s[t - d] : 0;
        __syncthreads();
        s[t] += x;
        __syncthreads();
    }
    if (i < n) {
        int excl = s[t] - v + base;
        off[i] = excl;
        cur[i] = excl;
    }
}

// =============== GEMM staging helpers ===============
__device__ __forceinline__ void load_a16(const float* __restrict__ A, int grow, int M, int seg,
                                         float* __restrict__ f) {
    if (grow < M) {
        const float* ap = A + (long)grow * KDIM + seg;
        #pragma unroll
        for (int q = 0; q < 4; ++q) {
            float4 a = *(const float4*)(ap + q * 4);
            f[q * 4 + 0] = a.x; f[q * 4 + 1] = a.y;
            f[q * 4 + 2] = a.z; f[q * 4 + 3] = a.w;
        }
    } else {
        #pragma unroll
        for (int i = 0; i < 16; ++i) f[i] = 0.f;
    }
}

__device__ __forceinline__ void split_store16(const float* __restrict__ f,
                                              ushort* __restrict__ Ahi, ushort* __restrict__ Alo,
                                              int m, int seg) {
    ushort h[16], l[16];
    #pragma unroll
    for (int i = 0; i < 16; ++i) split_bf16(f[i], h[i], l[i]);
    #pragma unroll
    for (int q = 0; q < 2; ++q) {
        uint4 hw, lw;
        hw.x = (unsigned)h[q*8+0] | ((unsigned)h[q*8+1] << 16);
        hw.y = (unsigned)h[q*8+2] | ((unsigned)h[q*8+3] << 16);
        hw.z = (unsigned)h[q*8+4] | ((unsigned)h[q*8+5] << 16);
        hw.w = (unsigned)h[q*8+6] | ((unsigned)h[q*8+7] << 16);
        lw.x = (unsigned)l[q*8+0] | ((unsigned)l[q*8+1] << 16);
        lw.y = (unsigned)l[q*8+2] | ((unsigned)l[q*8+3] << 16);
        lw.z = (unsigned)l[q*8+4] | ((unsigned)l[q*8+5] << 16);
        lw.w = (unsigned)l[q*8+6] | ((unsigned)l[q*8+7] << 16);
        *(uint4*)&Ahi[m * APAD + seg + q * 8] = hw;
        *(uint4*)&Alo[m * APAD + seg + q * 8] = lw;
    }
}

// plane staging: pure copy (split precomputed by agg)
__device__ __forceinline__ void load_pl(const ushort* __restrict__ Phi, const ushort* __restrict__ Plo,
                                        int grow, int M, int seg, uint4* __restrict__ r) {
    if (grow < M) {
        const uint4* ph = (const uint4*)(Phi + (long)grow * KDIM + seg);
        const uint4* pl = (const uint4*)(Plo + (long)grow * KDIM + seg);
        r[0] = ph[0]; r[1] = ph[1];
        r[2] = pl[0]; r[3] = pl[1];
    } else {
        uint4 z = {0, 0, 0, 0};
        r[0] = r[1] = r[2] = r[3] = z;
    }
}

__device__ __forceinline__ void store_pl(const uint4* __restrict__ r,
                                         ushort* __restrict__ Ahi, ushort* __restrict__ Alo,
                                         int m, int seg) {
    *(uint4*)&Ahi[m * APAD + seg] = r[0];
    *(uint4*)&Ahi[m * APAD + seg + 8] = r[1];
    *(uint4*)&Alo[m * APAD + seg] = r[2];
    *(uint4*)&Alo[m * APAD + seg + 8] = r[3];
}

// =============== wide GEMM core macros (B in regs, dbuf LDS, steal loop) ===============
#define WIDE_MFMA_TILE()                                                                      \
    f32x4 acc[2][2] = {};                                                                     \
    _Pragma("unroll")                                                                         \
    for (int c = 0; c < 4; ++c) {                                                             \
        const int k0 = c * 32 + quad * 8;                                                     \
        bf16x8 ah[2], al[2];                                                                  \
        _Pragma("unroll")                                                                     \
        for (int r = 0; r < 2; ++r) {                                                         \
            const int off = (16 * r + lane16) * APAD + k0;                                    \
            ah[r] = *(const bf16x8*)&AH[off];                                                 \
            al[r] = *(const bf16x8*)&AL[off];                                                 \
        }                                                                                     \
        _Pragma("unroll")                                                                     \
        for (int ct = 0; ct < 2; ++ct) {                                                      \
            _Pragma("unroll")                                                                 \
            for (int r = 0; r < 2; ++r) {                                                     \
                acc[r][ct] = __builtin_amdgcn_mfma_f32_16x16x32_bf16(Bh[c][ct], ah[r], acc[r][ct], 0, 0, 0); \
                acc[r][ct] = __builtin_amdgcn_mfma_f32_16x16x32_bf16(Bl[c][ct], ah[r], acc[r][ct], 0, 0, 0); \
                acc[r][ct] = __builtin_amdgcn_mfma_f32_16x16x32_bf16(Bh[c][ct], al[r], acc[r][ct], 0, 0, 0); \
            }                                                                                 \
        }                                                                                     \
    }

#define WIDE_STORE_TILE()                                                                     \
    _Pragma("unroll")                                                                         \
    for (int ct = 0; ct < 2; ++ct) {                                                          \
        const int colL = wave * 32 + 16 * ct + quad * 4;                                      \
        _Pragma("unroll")                                                                     \
        for (int r = 0; r < 2; ++r) {                                                         \
            const int row = rt * 32 + 16 * r + lane16;                                        \
            if (row < M) {                                                                    \
                if (half == 0) {                                                              \
                    *(f32x4*)(S + (long)row * 128 + colL) = acc[r][ct] + bv[ct];              \
                } else {                                                                      \
                    u16x4 t4;                                                                 \
                    _Pragma("unroll")                                                         \
                    for (int i = 0; i < 4; ++i) t4[i] = rne_bf16(acc[r][ct][i]);              \
                    *(u16x4*)(T + (long)row * 128 + colL) = t4;                               \
                }                                                                             \
            }                                                                                 \
        }                                                                                     \
    }

#define WIDE_B_PROLOGUE()                                                                     \
    bf16x8 Bh[4][2], Bl[4][2];                                                                \
    _Pragma("unroll")                                                                         \
    for (int c = 0; c < 4; ++c) {                                                             \
        _Pragma("unroll")                                                                     \
        for (int ct = 0; ct < 2; ++ct) {                                                      \
            const long boff = (long)(colbase + 16 * ct + lane16) * KDIM + c * 32 + quad * 8;  \
            Bh[c][ct] = *(const bf16x8*)(Bth + boff);                                         \
            Bl[c][ct] = *(const bf16x8*)(Btl + boff);                                         \
        }                                                                                     \
    }                                                                                         \
    f32x4 bv[2] = {};                                                                         \
    if (half == 0) {                                                                          \
        _Pragma("unroll")                                                                     \
        for (int ct = 0; ct < 2; ++ct)                                                        \
            bv[ct] = *(const f32x4*)(bias + wave * 32 + 16 * ct + quad * 4);                  \
    }

// ---- L0: fp32 A staging + fill_csr riding in blocks [0,128) + tile stealing ----
__global__ __launch_bounds__(256, 3) void k_gemm_wide_f32_fill(
    const float* __restrict__ A,
    const ushort* __restrict__ Bth, const ushort* __restrict__ Btl,
    const float* __restrict__ bias,
    float* __restrict__ S, ushort* __restrict__ T, int M,
    const int* __restrict__ src, const int* __restrict__ dst,
    int* __restrict__ cur, int* __restrict__ ssrcb,
    int* __restrict__ ctr)
{
    __shared__ ushort AhiB[2][32 * APAD];
    __shared__ ushort AloB[2][32 * APAD];
    __shared__ int s_tile[2];

    if (blockIdx.x < 128) {   // fill_csr (hidden under GEMM)
        const int gtid = blockIdx.x * 256 + threadIdx.x;
        for (int e = gtid; e < N_EDGES; e += 128 * 256) {
            int p = atomicAdd(&cur[dst[e]], 1);
            ssrcb[p] = src[e];
        }
        return;
    }

    const int bid = blockIdx.x - 128;
    const int tid = threadIdx.x;
    const int wave = tid >> 6;
    const int lane = tid & 63;
    const int lane16 = lane & 15;
    const int quad = lane >> 4;
    const int half = bid & 1;
    const int colbase = half * 128 + wave * 32;
    const int ntiles = (M + 31) >> 5;
    const int m   = tid >> 3;
    const int seg = (tid & 7) * 16;
    int* myctr = ctr + half;

    WIDE_B_PROLOGUE();

    if (tid == 0) s_tile[0] = atomicAdd(myctr, 1);
    __syncthreads();
    int rt = s_tile[0];
    if (rt >= ntiles) return;   // block-uniform

    float fa[16];
    load_a16(A, rt * 32 + m, M, seg, fa);
    split_store16(fa, &AhiB[0][0], &AloB[0][0], m, seg);
    if (tid == 0) s_tile[1] = atomicAdd(myctr, 1);
    __syncthreads();
    int nrt = s_tile[1];

    int sp = 0, cur_b = 0;
    while (true) {
        float fn[16];
        if (nrt < ntiles) load_a16(A, nrt * 32 + m, M, seg, fn);

        const ushort* AH = &AhiB[cur_b][0];
        const ushort* AL = &AloB[cur_b][0];
        WIDE_MFMA_TILE();
        WIDE_STORE_TILE();

        if (nrt >= ntiles) break;
        if (tid == 0) s_tile[sp] = atomicAdd(myctr, 1);
        split_store16(fn, &AhiB[cur_b ^ 1][0], &AloB[cur_b ^ 1][0], m, seg);
        __syncthreads();
        rt = nrt;
        nrt = s_tile[sp];
        sp ^= 1;
        cur_b ^= 1;
    }
}

// ---- L1: pre-split plane A (pure-copy staging) + tile stealing ----
__global__ __launch_bounds__(256, 3) void k_gemm_wide_pl(
    const ushort* __restrict__ Phi, const ushort* __restrict__ Plo,
    const ushort* __restrict__ Bth, const ushort* __restrict__ Btl,
    const float* __restrict__ bias,
    float* __restrict__ S, ushort* __restrict__ T, int M,
    int* __restrict__ ctr)
{
    __shared__ ushort AhiB[2][32 * APAD];
    __shared__ ushort AloB[2][32 * APAD];
    __shared__ int s_tile[2];

    const int tid = threadIdx.x;
    const int wave = tid >> 6;
    const int lane = tid & 63;
    const int lane16 = lane & 15;
    const int quad = lane >> 4;
    const int half = blockIdx.x & 1;
    const int colbase = half * 128 + wave * 32;
    const int ntiles = (M + 31) >> 5;
    const int m   = tid >> 3;
    const int seg = (tid & 7) * 16;
    int* myctr = ctr + half;

    WIDE_B_PROLOGUE();

    if (tid == 0) s_tile[0] = atomicAdd(myctr, 1);
    __syncthreads();
    int rt = s_tile[0];
    if (rt >= ntiles) return;

    uint4 ra[4];
    load_pl(Phi, Plo, rt * 32 + m, M, seg, ra);
    store_pl(ra, &AhiB[0][0], &AloB[0][0], m, seg);
    if (tid == 0) s_tile[1] = atomicAdd(myctr, 1);
    __syncthreads();
    int nrt = s_tile[1];

    int sp = 0, cur_b = 0;
    while (true) {
        uint4 rn[4];
        if (nrt < ntiles) load_pl(Phi, Plo, nrt * 32 + m, M, seg, rn);

        const ushort* AH = &AhiB[cur_b][0];
        const ushort* AL = &AloB[cur_b][0];
        WIDE_MFMA_TILE();
        WIDE_STORE_TILE();

        if (nrt >= ntiles) break;
        if (tid == 0) s_tile[sp] = atomicAdd(myctr, 1);
        store_pl(rn, &AhiB[cur_b ^ 1][0], &AloB[cur_b ^ 1][0], m, seg);
        __syncthreads();
        rt = nrt;
        nrt = s_tile[sp];
        sp ^= 1;
        cur_b ^= 1;
    }
}

// ---- L2 narrow: dout=40 dual (80 cols), plane A, tile stealing ----
__global__ __launch_bounds__(256, 2) void k_gemm_narrow_pl(
    const ushort* __restrict__ Phi, const ushort* __restrict__ Plo,
    const ushort* __restrict__ Bth, const ushort* __restrict__ Btl,
    const float* __restrict__ bias,
    float* __restrict__ S, ushort* __restrict__ T, int M,
    int* __restrict__ ctr)
{
    __shared__ ushort AhiB[2][32 * APAD];
    __shared__ ushort AloB[2][32 * APAD];
    __shared__ int s_tile[2];

    const int tid = threadIdx.x;
    const int wave = tid >> 6;
    const int lane = tid & 63;
    const int lane16 = lane & 15;
    const int quad = lane >> 4;
    const int rtw = wave & 1;
    const int cg = wave >> 1;
    const int ctbase = cg * 3;
    const int nct = cg ? 2 : 3;
    const int ntiles = (M + 31) >> 5;
    const int m   = tid >> 3;
    const int seg = (tid & 7) * 16;

    bf16x8 Bh[4][3], Bl[4][3];
    #pragma unroll
    for (int c = 0; c < 4; ++c) {
        #pragma unroll
        for (int j = 0; j < 3; ++j) {
            if (j < nct) {
                const long boff = (long)(16 * (ctbase + j) + lane16) * KDIM + c * 32 + quad * 8;
                Bh[c][j] = *(const bf16x8*)(Bth + boff);
                Bl[c][j] = *(const bf16x8*)(Btl + boff);
            }
        }
    }

    if (tid == 0) s_tile[0] = atomicAdd(ctr, 1);
    __syncthreads();
    int rt = s_tile[0];
    if (rt >= ntiles) return;

    uint4 ra[4];
    load_pl(Phi, Plo, rt * 32 + m, M, seg, ra);
    store_pl(ra, &AhiB[0][0], &AloB[0][0], m, seg);
    if (tid == 0) s_tile[1] = atomicAdd(ctr, 1);
    __syncthreads();
    int nrt = s_tile[1];

    int sp = 0, cur_b = 0;
    while (true) {
        uint4 rn[4];
        if (nrt < ntiles) load_pl(Phi, Plo, nrt * 32 + m, M, seg, rn);

        const ushort* AH = &AhiB[cur_b][0];
        const ushort* AL = &AloB[cur_b][0];

        f32x4 acc[3] = {};
        #pragma unroll
        for (int c = 0; c < 4; ++c) {
            const int off = (rtw * 16 + lane16) * APAD + c * 32 + quad * 8;
            bf16x8 ah = *(const bf16x8*)&AH[off];
            bf16x8 al = *(const bf16x8*)&AL[off];
            #pragma unroll
            for (int j = 0; j < 3; ++j) {
                if (j < nct) {
                    acc[j] = __builtin_amdgcn_mfma_f32_16x16x32_bf16(Bh[c][j], ah, acc[j], 0, 0, 0);
                    acc[j] = __builtin_amdgcn_mfma_f32_16x16x32_bf16(Bl[c][j], ah, acc[j], 0, 0, 0);
                    acc[j] = __builtin_amdgcn_mfma_f32_16x16x32_bf16(Bh[c][j], al, acc[j], 0, 0, 0);
                }
            }
        }

        const int row = rt * 32 + rtw * 16 + lane16;
        #pragma unroll
        for (int j = 0; j < 3; ++j) {
            if (j < nct && row < M) {
                const int col0 = 16 * (ctbase + j) + quad * 4;
                if (col0 < 40) {
                    f32x4 bvv = *(const f32x4*)(bias + col0);
                    *(f32x4*)(S + (long)row * 40 + col0) = acc[j] + bvv;
                } else {
                    u16x4 t4;
                    #pragma unroll
                    for (int i = 0; i < 4; ++i) t4[i] = rne_bf16(acc[j][i]);
                    *(u16x4*)(T + (long)row * 40 + (col0 - 40)) = t4;
                }
            }
        }

        if (nrt >= ntiles) break;
        if (tid == 0) s_tile[sp] = atomicAdd(ctr, 1);
        store_pl(rn, &AhiB[cur_b ^ 1][0], &AloB[cur_b ^ 1][0], m, seg);
        __syncthreads();
        rt = nrt;
        nrt = s_tile[sp];
        sp ^= 1;
        cur_b ^= 1;
    }
}

// =============== aggregation: wave-per-node, writes pre-split hi/lo planes ===============
__global__ __launch_bounds__(256) void k_agg128_pl(
    const float* __restrict__ S, const ushort* __restrict__ T,
    const int* __restrict__ off, const int* __restrict__ ssrcb,
    ushort* __restrict__ Phi, ushort* __restrict__ Plo, int nnodes)
{
    const int node = (blockIdx.x * 256 + threadIdx.x) >> 6;
    if (node >= nnodes) return;
    const int lane = threadIdx.x & 63;
    const int slot = lane >> 4;
    const int col8 = (lane & 15) * 8;

    const int a = off[node];
    const int b = off[node + 1];

    f32x4 acc0a = {0,0,0,0}, acc0b = {0,0,0,0};
    f32x4 acc1a = {0,0,0,0}, acc1b = {0,0,0,0};

    int i = a;
    for (; i + 8 <= b; i += 8) {
        int s0 = ssrcb[i + slot];
        int s1 = ssrcb[i + 4 + slot];
        u16x8 v0 = *(const u16x8*)(T + (long)s0 * 128 + col8);
        u16x8 v1 = *(const u16x8*)(T + (long)s1 * 128 + col8);
        #pragma unroll
        for (int j = 0; j < 4; ++j) {
            acc0a[j] += bf16_to_f32(v0[j]);
            acc0b[j] += bf16_to_f32(v0[4 + j]);
            acc1a[j] += bf16_to_f32(v1[j]);
            acc1b[j] += bf16_to_f32(v1[4 + j]);
        }
    }
    for (; i < b; i += 4) {
        int e = i + slot;
        if (e < b) {
            int s = ssrcb[e];
            u16x8 v = *(const u16x8*)(T + (long)s * 128 + col8);
            #pragma unroll
            for (int j = 0; j < 4; ++j) {
                acc0a[j] += bf16_to_f32(v[j]);
                acc0b[j] += bf16_to_f32(v[4 + j]);
            }
        }
    }
    f32x4 accA = acc0a + acc1a;
    f32x4 accB = acc0b + acc1b;

    #pragma unroll
    for (int mm = 16; mm <= 32; mm <<= 1) {
        #pragma unroll
        for (int j = 0; j < 4; ++j) {
            accA[j] += __shfl_xor((float)accA[j], mm);
            accB[j] += __shfl_xor((float)accB[j], mm);
        }
    }

    if (slot == 0) {
        int deg = b - a;
        float scale = (deg > 0) ? (1.0f / (float)deg) : 0.f;
        f32x4 sA = *(const f32x4*)(S + (long)node * 128 + col8);
        f32x4 sB = *(const f32x4*)(S + (long)node * 128 + col8 + 4);
        f32x4 rA = sA + accA * scale;
        f32x4 rB = sB + accB * scale;
        #pragma unroll
        for (int j = 0; j < 4; ++j) {
            rA[j] = fmaxf(rA[j], 0.f);   // relu (only L0/L1 use this kernel)
            rB[j] = fmaxf(rB[j], 0.f);
        }
        u16x8 ph, pl;
        #pragma unroll
        for (int j = 0; j < 4; ++j) {
            ushort h, l;
            split_bf16(rA[j], h, l); ph[j] = h; pl[j] = l;
        }
        #pragma unroll
        for (int j = 0; j < 4; ++j) {
            ushort h, l;
            split_bf16(rB[j], h, l); ph[4 + j] = h; pl[4 + j] = l;
        }
        *(u16x8*)(Phi + (long)node * 128 + col8) = ph;
        *(u16x8*)(Plo + (long)node * 128 + col8) = pl;
    }
}

__global__ __launch_bounds__(256) void k_agg40(
    const float* __restrict__ S, const ushort* __restrict__ T,
    const int* __restrict__ off, const int* __restrict__ ssrcb,
    float* __restrict__ out, int nnodes)
{
    const int node = (blockIdx.x * 256 + threadIdx.x) >> 6;
    if (node >= nnodes) return;
    const int lane = threadIdx.x & 63;
    const bool active = lane < 60;
    const int slot = active ? (lane / 10) : 5;
    const int fi = lane % 10;
    const int fo = fi * 4;

    const int a = off[node];
    const int b = off[node + 1];

    f32x4 acc0 = {0,0,0,0}, acc1 = {0,0,0,0};

    int i = a;
    for (; i + 12 <= b; i += 12) {
        int s0 = ssrcb[i + slot];
        int s1 = ssrcb[i + 6 + slot];
        u16x4 v0 = *(const u16x4*)(T + (long)s0 * 40 + fo);
        u16x4 v1 = *(const u16x4*)(T + (long)s1 * 40 + fo);
        if (active) {
            #pragma unroll
            for (int j = 0; j < 4; ++j) {
                acc0[j] += bf16_to_f32(v0[j]);
                acc1[j] += bf16_to_f32(v1[j]);
            }
        }
    }
    for (; i < b; i += 6) {
        int e = i + slot;
        if (active && e < b) {
            int s = ssrcb[e];
            u16x4 v = *(const u16x4*)(T + (long)s * 40 + fo);
            #pragma unroll
            for (int j = 0; j < 4; ++j) acc0[j] += bf16_to_f32(v[j]);
        }
    }
    f32x4 acc = acc0 + acc1;

    f32x4 tot = acc;
    #pragma unroll
    for (int d = 10; d <= 50; d += 10) {
        int srcl = fi + d;
        #pragma unroll
        for (int j = 0; j < 4; ++j) tot[j] += __shfl((float)acc[j], srcl);
    }

    if (lane < 10) {
        int deg = b - a;
        float scale = (deg > 0) ? (1.0f / (float)deg) : 0.f;
        f32x4 s4 = *(const f32x4*)(S + (long)node * 40 + fo);
        f32x4 r = s4 + tot * scale;
        *(f32x4*)(out + (long)node * 40 + fo) = r;
    }
}

// =============== launch ===============

extern "C" void kernel_launch(void* const* d_in, const int* in_sizes, int n_in,
                              void* d_out, int out_size, void* d_ws, size_t ws_size,
                              hipStream_t stream) {
    const float* feat = (const float*)d_in[0];
    const int*   src  = (const int*)d_in[1];
    const int*   dst  = (const int*)d_in[2];
    const float* ws0  = (const float*)d_in[3];
    const float* wn0  = (const float*)d_in[4];
    const float* b0   = (const float*)d_in[5];
    const float* ws1  = (const float*)d_in[6];
    const float* wn1  = (const float*)d_in[7];
    const float* b1   = (const float*)d_in[8];
    const float* ws2  = (const float*)d_in[9];
    const float* wn2  = (const float*)d_in[10];
    const float* b2   = (const float*)d_in[11];

    const int N = N_NODES;

    char* ws = (char*)d_ws;
    int*    offsets = (int*)(ws + 0);
    int*    cursor  = (int*)(ws + 200704);
    int*    degi    = (int*)(ws + 401408);      // 200000 B, ends 601408
    int*    tctr    = (int*)(ws + 601408);      // 5 tile-steal counters (in degi memset range)
    int*    bsum    = (int*)(ws + 601600);
    int*    ssrcb   = (int*)(ws + 603648);
    ushort* Phi  = (ushort*)(ws + 3003904);     // 12.8 MB
    ushort* Plo  = (ushort*)(ws + 15803904);    // 12.8 MB
    float*  sbuf = (float*)(ws + 28603904);     // 25.6 MB fp32
    ushort* tbuf = (ushort*)(ws + 54203904);    // 12.8 MB bf16

    // B buffers in d_out scratch (dead before agg40's final write)
    ushort* Ball = (ushort*)d_out;
    ushort* Bth0 = Ball;
    ushort* Btl0 = Ball + 32768;
    ushort* Bth1 = Ball + 65536;
    ushort* Btl1 = Ball + 98304;
    ushort* Bth2 = Ball + 131072;
    ushort* Btl2 = Ball + 141312;

    // ---- K0/K1: zero deg + steal counters; count_deg || convert_w ----
    hipMemsetAsync(degi, 0, (size_t)N * sizeof(int) + 64, stream);  // covers tctr[0..4]
    k_prep<<<256, 256, 0, stream>>>(dst, degi, ws0, wn0, ws1, wn1, ws2, wn2,
                                    Bth0, Btl0, Bth1, Btl1, Bth2, Btl2);

    // ---- K2/K3: CSR offsets ----
    block_sums_kernel<<<NBLK, 256, 0, stream>>>(degi, bsum, N);
    scatter_fused_kernel<<<NBLK, 256, 0, stream>>>(degi, bsum, offsets, cursor, N, NBLK);

    const int ga = (N + 3) / 4;   // 12500 agg blocks

    // ---- layer 0: GEMM (fp32 feat) + fill riding; tiles work-stolen via tctr[0..1] ----
    k_gemm_wide_f32_fill<<<768, 256, 0, stream>>>(feat, Bth0, Btl0, b0, sbuf, tbuf, N,
                                                  src, dst, cursor, ssrcb, tctr);
    k_agg128_pl<<<ga, 256, 0, stream>>>(sbuf, tbuf, offsets, ssrcb, Phi, Plo, N);

    // ---- layer 1: plane GEMM; tiles via tctr[2..3] ----
    k_gemm_wide_pl<<<768, 256, 0, stream>>>(Phi, Plo, Bth1, Btl1, b1, sbuf, tbuf, N, tctr + 2);
    k_agg128_pl<<<ga, 256, 0, stream>>>(sbuf, tbuf, offsets, ssrcb, Phi, Plo, N);

    // ---- layer 2: narrow plane GEMM via tctr[4]; agg writes final output ----
    k_gemm_narrow_pl<<<512, 256, 0, stream>>>(Phi, Plo, Bth2, Btl2, b2, sbuf, tbuf, N, tctr + 4);
    k_agg40<<<ga, 256, 0, stream>>>(sbuf, tbuf, offsets, ssrcb, (float*)d_out, N);
}

// Round 11
// 276.123 us; speedup vs baseline: 1.2798x; 1.2798x over previous
//
#include <hip/hip_runtime.h>

#define N_NODES 50000
#define N_EDGES 600000
#define NBLK    196           // (N_NODES+255)/256
#define KDIM    128
#define APAD    136           // 128 + 8 ushorts pad (272B row stride -> 2-way banks, free)

typedef short bf16x8 __attribute__((ext_vector_type(8)));
typedef float f32x4  __attribute__((ext_vector_type(4)));
typedef unsigned short u16x8 __attribute__((ext_vector_type(8)));
typedef unsigned short u16x4 __attribute__((ext_vector_type(4)));

// ---------------- bf16 helpers (RNE) ----------------
__device__ inline ushort rne_bf16(float a) {
    union { float f; unsigned u; } v; v.f = a;
    return (ushort)((v.u + 0x7FFFu + ((v.u >> 16) & 1u)) >> 16);
}
__device__ inline float bf16_to_f32(ushort h) {
    return __uint_as_float((unsigned)h << 16);
}
__device__ inline void split_bf16(float a, ushort& hi, ushort& lo) {
    hi = rne_bf16(a);
    float hv = bf16_to_f32(hi);
    lo = rne_bf16(a - hv);
}

// =============== K1: fused count_deg || convert_w ===============
__global__ __launch_bounds__(256) void k_prep(
    const int* __restrict__ dst, int* __restrict__ degi,
    const float* __restrict__ ws0, const float* __restrict__ wn0,
    const float* __restrict__ ws1, const float* __restrict__ wn1,
    const float* __restrict__ ws2, const float* __restrict__ wn2,
    ushort* __restrict__ Bth0, ushort* __restrict__ Btl0,
    ushort* __restrict__ Bth1, ushort* __restrict__ Btl1,
    ushort* __restrict__ Bth2, ushort* __restrict__ Btl2)
{
    const int b = blockIdx.x, t = threadIdx.x;
    if (b < 192) {
        for (int e = b * 256 + t; e < N_EDGES; e += 192 * 256)
            atomicAdd(&degi[dst[e]], 1);
    } else {
        for (int i = (b - 192) * 256 + t; i < 592 * 128; i += 64 * 256) {
            int bb = i >> 7, k = i & 127;
            const float *Ws, *Wn;
            ushort *H, *L;
            int dout, n;
            if (bb < 256)      { n = bb;       dout = 128; Ws = ws0; Wn = wn0; H = Bth0; L = Btl0; }
            else if (bb < 512) { n = bb - 256; dout = 128; Ws = ws1; Wn = wn1; H = Bth1; L = Btl1; }
            else               { n = bb - 512; dout = 40;  Ws = ws2; Wn = wn2; H = Bth2; L = Btl2; }
            float w = (n < dout) ? Ws[(long)k * dout + n] : Wn[(long)k * dout + (n - dout)];
            ushort hi, lo;
            split_bf16(w, hi, lo);
            H[n * 128 + k] = hi;
            L[n * 128 + k] = lo;
        }
    }
}

// =============== CSR scan kernels ===============
__global__ __launch_bounds__(256) void block_sums_kernel(const int* __restrict__ deg,
                                                         int* __restrict__ bsum, int n) {
    __shared__ int s[256];
    int t = threadIdx.x;
    int i = blockIdx.x * 256 + t;
    s[t] = (i < n) ? deg[i] : 0;
    __syncthreads();
    #pragma unroll
    for (int d = 128; d > 0; d >>= 1) {
        if (t < d) s[t] += s[t + d];
        __syncthreads();
    }
    if (t == 0) bsum[blockIdx.x] = s[0];
}

__global__ __launch_bounds__(256) void scatter_fused_kernel(const int* __restrict__ deg,
                                                            const int* __restrict__ bsum,
                                                            int* __restrict__ off,
                                                            int* __restrict__ cur,
                                                            int n, int nb) {
    __shared__ int s[256];
    int t = threadIdx.x;

    int bv = (t < nb) ? bsum[t] : 0;
    s[t] = bv;
    __syncthreads();
    #pragma unroll
    for (int d = 1; d < 256; d <<= 1) {
        int x = (t >= d) ? s[t - d] : 0;
        __syncthreads();
        s[t] += x;
        __syncthreads();
    }
    int base = (blockIdx.x > 0) ? s[blockIdx.x - 1] : 0;
    if (blockIdx.x == 0 && t == 0) off[n] = s[255];
    __syncthreads();

    int i = blockIdx.x * 256 + t;
    int v = (i < n) ? deg[i] : 0;
    s[t] = v;
    __syncthreads();
    #pragma unroll
    for (int d = 1; d < 256; d <<= 1) {
        int x = (t >= d) ? s[t - d] : 0;
        __syncthreads();
        s[t] += x;
        __syncthreads();
    }
    if (i < n) {
        int excl = s[t] - v + base;
        off[i] = excl;
        cur[i] = excl;
    }
}

// =============== GEMM staging helpers ===============
__device__ __forceinline__ void load_a16(const float* __restrict__ A, int grow, int M, int seg,
                                         float* __restrict__ f) {
    if (grow < M) {
        const float* ap = A + (long)grow * KDIM + seg;
        #pragma unroll
        for (int q = 0; q < 4; ++q) {
            float4 a = *(const float4*)(ap + q * 4);
            f[q * 4 + 0] = a.x; f[q * 4 + 1] = a.y;
            f[q * 4 + 2] = a.z; f[q * 4 + 3] = a.w;
        }
    } else {
        #pragma unroll
        for (int i = 0; i < 16; ++i) f[i] = 0.f;
    }
}

__device__ __forceinline__ void split_store16(const float* __restrict__ f,
                                              ushort* __restrict__ Ahi, ushort* __restrict__ Alo,
                                              int m, int seg) {
    ushort h[16], l[16];
    #pragma unroll
    for (int i = 0; i < 16; ++i) split_bf16(f[i], h[i], l[i]);
    #pragma unroll
    for (int q = 0; q < 2; ++q) {
        uint4 hw, lw;
        hw.x = (unsigned)h[q*8+0] | ((unsigned)h[q*8+1] << 16);
        hw.y = (unsigned)h[q*8+2] | ((unsigned)h[q*8+3] << 16);
        hw.z = (unsigned)h[q*8+4] | ((unsigned)h[q*8+5] << 16);
        hw.w = (unsigned)h[q*8+6] | ((unsigned)h[q*8+7] << 16);
        lw.x = (unsigned)l[q*8+0] | ((unsigned)l[q*8+1] << 16);
        lw.y = (unsigned)l[q*8+2] | ((unsigned)l[q*8+3] << 16);
        lw.z = (unsigned)l[q*8+4] | ((unsigned)l[q*8+5] << 16);
        lw.w = (unsigned)l[q*8+6] | ((unsigned)l[q*8+7] << 16);
        *(uint4*)&Ahi[m * APAD + seg + q * 8] = hw;
        *(uint4*)&Alo[m * APAD + seg + q * 8] = lw;
    }
}

// async global->LDS staging of one 32x128 plane tile (hi 8KB + lo 8KB, linear).
// LDS dest is wave-uniform base + lane*16 (HW); global src is per-lane.
// Global plane layout is pre-swizzled (agg writes chunk (lane&15)^(node&7)),
// so linear copy lands the swizzled layout in LDS; reads apply the same XOR.
__device__ __forceinline__ void stage_pl_async(const ushort* __restrict__ Phi,
                                               const ushort* __restrict__ Plo,
                                               int tilebase, int wave, int lane,
                                               ushort* lds16k) {
    const char* gsrc = (wave < 2)
        ? (const char*)(Phi + (long)tilebase * KDIM) + wave * 4096
        : (const char*)(Plo + (long)tilebase * KDIM) + (wave - 2) * 4096;
    char* ldst = (char*)lds16k + wave * 4096;
    #pragma unroll
    for (int j = 0; j < 4; ++j) {
        __builtin_amdgcn_global_load_lds(
            (const __attribute__((address_space(1))) unsigned int*)(const void*)(gsrc + j * 1024 + lane * 16),
            (__attribute__((address_space(3))) unsigned int*)(void*)(ldst + j * 1024),
            16, 0, 0);
    }
}

// =============== wide GEMM core macros ===============
// APAD variant (L0, manual split staging):
#define WIDE_MFMA_TILE()                                                                      \
    f32x4 acc[2][2] = {};                                                                     \
    _Pragma("unroll")                                                                         \
    for (int c = 0; c < 4; ++c) {                                                             \
        const int k0 = c * 32 + quad * 8;                                                     \
        bf16x8 ah[2], al[2];                                                                  \
        _Pragma("unroll")                                                                     \
        for (int r = 0; r < 2; ++r) {                                                         \
            const int off = (16 * r + lane16) * APAD + k0;                                    \
            ah[r] = *(const bf16x8*)&AH[off];                                                 \
            al[r] = *(const bf16x8*)&AL[off];                                                 \
        }                                                                                     \
        _Pragma("unroll")                                                                     \
        for (int ct = 0; ct < 2; ++ct) {                                                      \
            _Pragma("unroll")                                                                 \
            for (int r = 0; r < 2; ++r) {                                                     \
                acc[r][ct] = __builtin_amdgcn_mfma_f32_16x16x32_bf16(Bh[c][ct], ah[r], acc[r][ct], 0, 0, 0); \
                acc[r][ct] = __builtin_amdgcn_mfma_f32_16x16x32_bf16(Bl[c][ct], ah[r], acc[r][ct], 0, 0, 0); \
                acc[r][ct] = __builtin_amdgcn_mfma_f32_16x16x32_bf16(Bh[c][ct], al[r], acc[r][ct], 0, 0, 0); \
            }                                                                                 \
        }                                                                                     \
    }

// swizzled linear variant (L1 planes via global_load_lds):
#define WIDE_MFMA_TILE_SW()                                                                   \
    f32x4 acc[2][2] = {};                                                                     \
    _Pragma("unroll")                                                                         \
    for (int c = 0; c < 4; ++c) {                                                             \
        bf16x8 ah[2], al[2];                                                                  \
        _Pragma("unroll")                                                                     \
        for (int r = 0; r < 2; ++r) {                                                         \
            const int p = (quad + 4 * c) ^ (lane16 & 7);                                      \
            const int off = (16 * r + lane16) * 128 + p * 8;                                  \
            ah[r] = *(const bf16x8*)&AH[off];                                                 \
            al[r] = *(const bf16x8*)&AL[off];                                                 \
        }                                                                                     \
        _Pragma("unroll")                                                                     \
        for (int ct = 0; ct < 2; ++ct) {                                                      \
            _Pragma("unroll")                                                                 \
            for (int r = 0; r < 2; ++r) {                                                     \
                acc[r][ct] = __builtin_amdgcn_mfma_f32_16x16x32_bf16(Bh[c][ct], ah[r], acc[r][ct], 0, 0, 0); \
                acc[r][ct] = __builtin_amdgcn_mfma_f32_16x16x32_bf16(Bl[c][ct], ah[r], acc[r][ct], 0, 0, 0); \
                acc[r][ct] = __builtin_amdgcn_mfma_f32_16x16x32_bf16(Bh[c][ct], al[r], acc[r][ct], 0, 0, 0); \
            }                                                                                 \
        }                                                                                     \
    }

#define WIDE_STORE_TILE()                                                                     \
    _Pragma("unroll")                                                                         \
    for (int ct = 0; ct < 2; ++ct) {                                                          \
        const int colL = wave * 32 + 16 * ct + quad * 4;                                      \
        _Pragma("unroll")                                                                     \
        for (int r = 0; r < 2; ++r) {                                                         \
            const int row = rt * 32 + 16 * r + lane16;                                        \
            if (row < M) {                                                                    \
                if (half == 0) {                                                              \
                    *(f32x4*)(S + (long)row * 128 + colL) = acc[r][ct] + bv[ct];              \
                } else {                                                                      \
                    u16x4 t4;                                                                 \
                    _Pragma("unroll")                                                         \
                    for (int i = 0; i < 4; ++i) t4[i] = rne_bf16(acc[r][ct][i]);              \
                    *(u16x4*)(T + (long)row * 128 + colL) = t4;                               \
                }                                                                             \
            }                                                                                 \
        }                                                                                     \
    }

#define WIDE_B_PROLOGUE()                                                                     \
    bf16x8 Bh[4][2], Bl[4][2];                                                                \
    _Pragma("unroll")                                                                         \
    for (int c = 0; c < 4; ++c) {                                                             \
        _Pragma("unroll")                                                                     \
        for (int ct = 0; ct < 2; ++ct) {                                                      \
            const long boff = (long)(colbase + 16 * ct + lane16) * KDIM + c * 32 + quad * 8;  \
            Bh[c][ct] = *(const bf16x8*)(Bth + boff);                                         \
            Bl[c][ct] = *(const bf16x8*)(Btl + boff);                                         \
        }                                                                                     \
    }                                                                                         \
    f32x4 bv[2] = {};                                                                         \
    if (half == 0) {                                                                          \
        _Pragma("unroll")                                                                     \
        for (int ct = 0; ct < 2; ++ct)                                                        \
            bv[ct] = *(const f32x4*)(bias + wave * 32 + 16 * ct + quad * 4);                  \
    }

// ---- L0: fp32 A staging + fill_csr riding in blocks [0,128) (r8 structure) ----
__global__ __launch_bounds__(256, 3) void k_gemm_wide_f32_fill(
    const float* __restrict__ A,
    const ushort* __restrict__ Bth, const ushort* __restrict__ Btl,
    const float* __restrict__ bias,
    float* __restrict__ S, ushort* __restrict__ T, int M,
    const int* __restrict__ src, const int* __restrict__ dst,
    int* __restrict__ cur, int* __restrict__ ssrcb)
{
    __shared__ ushort AhiB[2][32 * APAD];
    __shared__ ushort AloB[2][32 * APAD];

    if (blockIdx.x < 128) {   // fill_csr (hidden under GEMM)
        const int gtid = blockIdx.x * 256 + threadIdx.x;
        for (int e = gtid; e < N_EDGES; e += 128 * 256) {
            int p = atomicAdd(&cur[dst[e]], 1);
            ssrcb[p] = src[e];
        }
        return;
    }

    const int bid = blockIdx.x - 128;             // 0..639
    const int tid = threadIdx.x;
    const int wave = tid >> 6;
    const int lane = tid & 63;
    const int lane16 = lane & 15;
    const int quad = lane >> 4;
    const int half = bid & 1;
    const int colbase = half * 128 + wave * 32;
    const int ntiles = (M + 31) >> 5;
    const int bstride = 320;                      // 640 GEMM blocks / 2 halves
    const int m   = tid >> 3;
    const int seg = (tid & 7) * 16;

    WIDE_B_PROLOGUE();

    int rt = bid >> 1;
    if (rt >= ntiles) return;

    float fa[16];
    load_a16(A, rt * 32 + m, M, seg, fa);
    split_store16(fa, &AhiB[0][0], &AloB[0][0], m, seg);
    __syncthreads();

    int cur_b = 0;
    while (true) {
        const int nrt = rt + bstride;
        float fn[16];
        if (nrt < ntiles) load_a16(A, nrt * 32 + m, M, seg, fn);

        const ushort* AH = &AhiB[cur_b][0];
        const ushort* AL = &AloB[cur_b][0];
        WIDE_MFMA_TILE();
        WIDE_STORE_TILE();

        if (nrt >= ntiles) break;
        split_store16(fn, &AhiB[cur_b ^ 1][0], &AloB[cur_b ^ 1][0], m, seg);
        __syncthreads();
        cur_b ^= 1;
        rt = nrt;
    }
}

// ---- L1: plane A via global_load_lds (linear LDS, swizzled layout) ----
__global__ __launch_bounds__(256, 3) void k_gemm_wide_pl(
    const ushort* __restrict__ Phi, const ushort* __restrict__ Plo,
    const ushort* __restrict__ Bth, const ushort* __restrict__ Btl,
    const float* __restrict__ bias,
    float* __restrict__ S, ushort* __restrict__ T, int M)
{
    __shared__ ushort AB[2][8192];   // [buf][hi 8KB | lo 8KB], linear

    const int tid = threadIdx.x;
    const int wave = tid >> 6;
    const int lane = tid & 63;
    const int lane16 = lane & 15;
    const int quad = lane >> 4;
    const int half = blockIdx.x & 1;
    const int colbase = half * 128 + wave * 32;
    const int ntiles = (M + 31) >> 5;
    const int bstride = gridDim.x >> 1;

    WIDE_B_PROLOGUE();

    int rt = blockIdx.x >> 1;
    if (rt >= ntiles) return;

    stage_pl_async(Phi, Plo, rt * 32, wave, lane, &AB[0][0]);
    __syncthreads();   // drains vmcnt -> buf0 ready

    int cur_b = 0;
    while (true) {
        const int nrt = rt + bstride;
        if (nrt < ntiles)
            stage_pl_async(Phi, Plo, nrt * 32, wave, lane, &AB[cur_b ^ 1][0]);  // in flight under MFMAs

        const ushort* AH = &AB[cur_b][0];
        const ushort* AL = AH + 4096;
        WIDE_MFMA_TILE_SW();
        WIDE_STORE_TILE();

        if (nrt >= ntiles) break;
        __syncthreads();   // readers of buf done + next buf's loads drained
        cur_b ^= 1;
        rt = nrt;
    }
}

// ---- L2 narrow: dout=40 dual (80 cols), plane A via global_load_lds ----
__global__ __launch_bounds__(256, 2) void k_gemm_narrow_pl(
    const ushort* __restrict__ Phi, const ushort* __restrict__ Plo,
    const ushort* __restrict__ Bth, const ushort* __restrict__ Btl,
    const float* __restrict__ bias,
    float* __restrict__ S, ushort* __restrict__ T, int M)
{
    __shared__ ushort AB[2][8192];

    const int tid = threadIdx.x;
    const int wave = tid >> 6;
    const int lane = tid & 63;
    const int lane16 = lane & 15;
    const int quad = lane >> 4;
    const int rtw = wave & 1;
    const int cg = wave >> 1;
    const int ctbase = cg * 3;
    const int nct = cg ? 2 : 3;
    const int ntiles = (M + 31) >> 5;

    bf16x8 Bh[4][3], Bl[4][3];
    #pragma unroll
    for (int c = 0; c < 4; ++c) {
        #pragma unroll
        for (int j = 0; j < 3; ++j) {
            if (j < nct) {
                const long boff = (long)(16 * (ctbase + j) + lane16) * KDIM + c * 32 + quad * 8;
                Bh[c][j] = *(const bf16x8*)(Bth + boff);
                Bl[c][j] = *(const bf16x8*)(Btl + boff);
            }
        }
    }

    int rt = blockIdx.x;
    if (rt >= ntiles) return;

    stage_pl_async(Phi, Plo, rt * 32, wave, lane, &AB[0][0]);
    __syncthreads();

    int cur_b = 0;
    while (true) {
        const int nrt = rt + gridDim.x;
        if (nrt < ntiles)
            stage_pl_async(Phi, Plo, nrt * 32, wave, lane, &AB[cur_b ^ 1][0]);

        const ushort* AH = &AB[cur_b][0];
        const ushort* AL = AH + 4096;

        f32x4 acc[3] = {};
        #pragma unroll
        for (int c = 0; c < 4; ++c) {
            const int p = (quad + 4 * c) ^ (lane16 & 7);
            const int off = (rtw * 16 + lane16) * 128 + p * 8;
            bf16x8 ah = *(const bf16x8*)&AH[off];
            bf16x8 al = *(const bf16x8*)&AL[off];
            #pragma unroll
            for (int j = 0; j < 3; ++j) {
                if (j < nct) {
                    acc[j] = __builtin_amdgcn_mfma_f32_16x16x32_bf16(Bh[c][j], ah, acc[j], 0, 0, 0);
                    acc[j] = __builtin_amdgcn_mfma_f32_16x16x32_bf16(Bl[c][j], ah, acc[j], 0, 0, 0);
                    acc[j] = __builtin_amdgcn_mfma_f32_16x16x32_bf16(Bh[c][j], al, acc[j], 0, 0, 0);
                }
            }
        }

        const int row = rt * 32 + rtw * 16 + lane16;
        #pragma unroll
        for (int j = 0; j < 3; ++j) {
            if (j < nct && row < M) {
                const int col0 = 16 * (ctbase + j) + quad * 4;
                if (col0 < 40) {
                    f32x4 bvv = *(const f32x4*)(bias + col0);
                    *(f32x4*)(S + (long)row * 40 + col0) = acc[j] + bvv;
                } else {
                    u16x4 t4;
                    #pragma unroll
                    for (int i = 0; i < 4; ++i) t4[i] = rne_bf16(acc[j][i]);
                    *(u16x4*)(T + (long)row * 40 + (col0 - 40)) = t4;
                }
            }
        }

        if (nrt >= ntiles) break;
        __syncthreads();
        cur_b ^= 1;
        rt = nrt;
    }
}

// =============== aggregation: wave-per-node, writes SWIZZLED hi/lo planes ===============
__global__ __launch_bounds__(256) void k_agg128_pl(
    const float* __restrict__ S, const ushort* __restrict__ T,
    const int* __restrict__ off, const int* __restrict__ ssrcb,
    ushort* __restrict__ Phi, ushort* __restrict__ Plo, int nnodes)
{
    const int node = (blockIdx.x * 256 + threadIdx.x) >> 6;
    if (node >= nnodes) return;
    const int lane = threadIdx.x & 63;
    const int slot = lane >> 4;
    const int col8 = (lane & 15) * 8;

    const int a = off[node];
    const int b = off[node + 1];

    f32x4 acc0a = {0,0,0,0}, acc0b = {0,0,0,0};
    f32x4 acc1a = {0,0,0,0}, acc1b = {0,0,0,0};

    int i = a;
    for (; i + 8 <= b; i += 8) {
        int s0 = ssrcb[i + slot];
        int s1 = ssrcb[i + 4 + slot];
        u16x8 v0 = *(const u16x8*)(T + (long)s0 * 128 + col8);
        u16x8 v1 = *(const u16x8*)(T + (long)s1 * 128 + col8);
        #pragma unroll
        for (int j = 0; j < 4; ++j) {
            acc0a[j] += bf16_to_f32(v0[j]);
            acc0b[j] += bf16_to_f32(v0[4 + j]);
            acc1a[j] += bf16_to_f32(v1[j]);
            acc1b[j] += bf16_to_f32(v1[4 + j]);
        }
    }
    for (; i < b; i += 4) {
        int e = i + slot;
        if (e < b) {
            int s = ssrcb[e];
            u16x8 v = *(const u16x8*)(T + (long)s * 128 + col8);
            #pragma unroll
            for (int j = 0; j < 4; ++j) {
                acc0a[j] += bf16_to_f32(v[j]);
                acc0b[j] += bf16_to_f32(v[4 + j]);
            }
        }
    }
    f32x4 accA = acc0a + acc1a;
    f32x4 accB = acc0b + acc1b;

    #pragma unroll
    for (int mm = 16; mm <= 32; mm <<= 1) {
        #pragma unroll
        for (int j = 0; j < 4; ++j) {
            accA[j] += __shfl_xor((float)accA[j], mm);
            accB[j] += __shfl_xor((float)accB[j], mm);
        }
    }

    if (slot == 0) {
        int deg = b - a;
        float scale = (deg > 0) ? (1.0f / (float)deg) : 0.f;
        f32x4 sA = *(const f32x4*)(S + (long)node * 128 + col8);
        f32x4 sB = *(const f32x4*)(S + (long)node * 128 + col8 + 4);
        f32x4 rA = sA + accA * scale;
        f32x4 rB = sB + accB * scale;
        #pragma unroll
        for (int j = 0; j < 4; ++j) {
            rA[j] = fmaxf(rA[j], 0.f);   // relu (only L0/L1 use this kernel)
            rB[j] = fmaxf(rB[j], 0.f);
        }
        u16x8 ph, pl;
        #pragma unroll
        for (int j = 0; j < 4; ++j) {
            ushort h, l;
            split_bf16(rA[j], h, l); ph[j] = h; pl[j] = l;
        }
        #pragma unroll
        for (int j = 0; j < 4; ++j) {
            ushort h, l;
            split_bf16(rB[j], h, l); ph[4 + j] = h; pl[4 + j] = l;
        }
        // swizzled chunk position: XOR feature-chunk with node&7 (matches GEMM ds_read XOR)
        const int colsw = (((lane & 15) ^ (node & 7)) * 8);
        *(u16x8*)(Phi + (long)node * 128 + colsw) = ph;
        *(u16x8*)(Plo + (long)node * 128 + colsw) = pl;
    }
}

__global__ __launch_bounds__(256) void k_agg40(
    const float* __restrict__ S, const ushort* __restrict__ T,
    const int* __restrict__ off, const int* __restrict__ ssrcb,
    float* __restrict__ out, int nnodes)
{
    const int node = (blockIdx.x * 256 + threadIdx.x) >> 6;
    if (node >= nnodes) return;
    const int lane = threadIdx.x & 63;
    const bool active = lane < 60;
    const int slot = active ? (lane / 10) : 5;
    const int fi = lane % 10;
    const int fo = fi * 4;

    const int a = off[node];
    const int b = off[node + 1];

    f32x4 acc0 = {0,0,0,0}, acc1 = {0,0,0,0};

    int i = a;
    for (; i + 12 <= b; i += 12) {
        int s0 = ssrcb[i + slot];
        int s1 = ssrcb[i + 6 + slot];
        u16x4 v0 = *(const u16x4*)(T + (long)s0 * 40 + fo);
        u16x4 v1 = *(const u16x4*)(T + (long)s1 * 40 + fo);
        if (active) {
            #pragma unroll
            for (int j = 0; j < 4; ++j) {
                acc0[j] += bf16_to_f32(v0[j]);
                acc1[j] += bf16_to_f32(v1[j]);
            }
        }
    }
    for (; i < b; i += 6) {
        int e = i + slot;
        if (active && e < b) {
            int s = ssrcb[e];
            u16x4 v = *(const u16x4*)(T + (long)s * 40 + fo);
            #pragma unroll
            for (int j = 0; j < 4; ++j) acc0[j] += bf16_to_f32(v[j]);
        }
    }
    f32x4 acc = acc0 + acc1;

    f32x4 tot = acc;
    #pragma unroll
    for (int d = 10; d <= 50; d += 10) {
        int srcl = fi + d;
        #pragma unroll
        for (int j = 0; j < 4; ++j) tot[j] += __shfl((float)acc[j], srcl);
    }

    if (lane < 10) {
        int deg = b - a;
        float scale = (deg > 0) ? (1.0f / (float)deg) : 0.f;
        f32x4 s4 = *(const f32x4*)(S + (long)node * 40 + fo);
        f32x4 r = s4 + tot * scale;
        *(f32x4*)(out + (long)node * 40 + fo) = r;
    }
}

// =============== launch ===============

extern "C" void kernel_launch(void* const* d_in, const int* in_sizes, int n_in,
                              void* d_out, int out_size, void* d_ws, size_t ws_size,
                              hipStream_t stream) {
    const float* feat = (const float*)d_in[0];
    const int*   src  = (const int*)d_in[1];
    const int*   dst  = (const int*)d_in[2];
    const float* ws0  = (const float*)d_in[3];
    const float* wn0  = (const float*)d_in[4];
    const float* b0   = (const float*)d_in[5];
    const float* ws1  = (const float*)d_in[6];
    const float* wn1  = (const float*)d_in[7];
    const float* b1   = (const float*)d_in[8];
    const float* ws2  = (const float*)d_in[9];
    const float* wn2  = (const float*)d_in[10];
    const float* b2   = (const float*)d_in[11];

    const int N = N_NODES;

    char* ws = (char*)d_ws;
    int*    offsets = (int*)(ws + 0);
    int*    cursor  = (int*)(ws + 200704);
    int*    degi    = (int*)(ws + 401408);
    int*    bsum    = (int*)(ws + 601600);
    int*    ssrcb   = (int*)(ws + 603648);
    ushort* Phi  = (ushort*)(ws + 3003904);   // 12.8 MB (swizzled planes)
    ushort* Plo  = (ushort*)(ws + 15803904);  // 12.8 MB
    float*  sbuf = (float*)(ws + 28603904);   // 25.6 MB fp32
    ushort* tbuf = (ushort*)(ws + 54203904);  // 12.8 MB bf16

    // B buffers in d_out scratch (dead before agg40's final write)
    ushort* Ball = (ushort*)d_out;
    ushort* Bth0 = Ball;
    ushort* Btl0 = Ball + 32768;
    ushort* Bth1 = Ball + 65536;
    ushort* Btl1 = Ball + 98304;
    ushort* Bth2 = Ball + 131072;
    ushort* Btl2 = Ball + 141312;

    // ---- K0/K1: zero deg; count_deg || convert_w ----
    hipMemsetAsync(degi, 0, (size_t)N * sizeof(int), stream);
    k_prep<<<256, 256, 0, stream>>>(dst, degi, ws0, wn0, ws1, wn1, ws2, wn2,
                                    Bth0, Btl0, Bth1, Btl1, Bth2, Btl2);

    // ---- K2/K3: CSR offsets ----
    block_sums_kernel<<<NBLK, 256, 0, stream>>>(degi, bsum, N);
    scatter_fused_kernel<<<NBLK, 256, 0, stream>>>(degi, bsum, offsets, cursor, N, NBLK);

    const int ga = (N + 3) / 4;   // 12500 agg blocks

    // ---- layer 0: GEMM (fp32 feat) with fill_csr riding in blocks [0,128) ----
    k_gemm_wide_f32_fill<<<768, 256, 0, stream>>>(feat, Bth0, Btl0, b0, sbuf, tbuf, N,
                                                  src, dst, cursor, ssrcb);
    k_agg128_pl<<<ga, 256, 0, stream>>>(sbuf, tbuf, offsets, ssrcb, Phi, Plo, N);

    // ---- layer 1: plane GEMM (global_load_lds staging) ----
    k_gemm_wide_pl<<<768, 256, 0, stream>>>(Phi, Plo, Bth1, Btl1, b1, sbuf, tbuf, N);
    k_agg128_pl<<<ga, 256, 0, stream>>>(sbuf, tbuf, offsets, ssrcb, Phi, Plo, N);

    // ---- layer 2: narrow plane GEMM, agg writes final output ----
    k_gemm_narrow_pl<<<512, 256, 0, stream>>>(Phi, Plo, Bth2, Btl2, b2, sbuf, tbuf, N);
    k_agg40<<<ga, 256, 0, stream>>>(sbuf, tbuf, offsets, ssrcb, (float*)d_out, N);
}